// Round 19
// baseline (216.579 us; speedup 1.0000x reference)
//
#include <hip/hip_runtime.h>
#include <hip/hip_bf16.h>
#include <stdint.h>

#define SEQ_T 2048
#define NBATCH 4
#define CEMB 1024
#define NH 16
#define DH 64
#define MROWS 8192

typedef short bf16x8 __attribute__((ext_vector_type(8)));
typedef float f32x4 __attribute__((ext_vector_type(4)));
typedef float f32x16 __attribute__((ext_vector_type(16)));
typedef unsigned short u16x8 __attribute__((ext_vector_type(8)));
typedef unsigned int u32x2 __attribute__((ext_vector_type(2)));

__device__ __forceinline__ unsigned short f2bf(float f) {
    union { float f; unsigned u; } v; v.f = f;
    unsigned r = (v.u + 0x7FFFu + ((v.u >> 16) & 1u)) >> 16;
    return (unsigned short)r;
}

__device__ __forceinline__ f32x4 mfma16(bf16x8 a, bf16x8 b, f32x4 c) {
    return __builtin_amdgcn_mfma_f32_16x16x32_bf16(a, b, c, 0, 0, 0);
}
__device__ __forceinline__ f32x16 mfma32(bf16x8 a, bf16x8 b, f32x16 c) {
    return __builtin_amdgcn_mfma_f32_32x32x16_bf16(a, b, c, 0, 0, 0);
}

__device__ __forceinline__ float exp2fast(float x) {
    float r; asm("v_exp_f32 %0, %1" : "=v"(r) : "v"(x)); return r;
}
// packed bf16 RNE convert: dst = {bf16(lo), bf16(hi)}
__device__ __forceinline__ unsigned cvtpk(float lo, float hi) {
    unsigned r;
    asm("v_cvt_pk_bf16_f32 %0, %1, %2" : "=v"(r) : "v"(lo), "v"(hi));
    return r;
}

#define GLL16(g, l) __builtin_amdgcn_global_load_lds( \
    (const __attribute__((address_space(1))) void*)(g), \
    (__attribute__((address_space(3))) void*)(l), 16, 0, 0)

// Single fused cast: X (2097152 f4) | Wqkv (786432 f4) | Wout (262144 f4)
__global__ __launch_bounds__(256)
void cast_all(const float* __restrict__ x, const float* __restrict__ w1,
              const float* __restrict__ w2,
              unsigned short* __restrict__ ox, unsigned short* __restrict__ o1,
              unsigned short* __restrict__ o2) {
    int i = blockIdx.x * blockDim.x + threadIdx.x;
    const float* src; unsigned short* dst; int off;
    if (i < 2097152)      { src = x;  dst = ox; off = i; }
    else if (i < 2883584) { src = w1; dst = o1; off = i - 2097152; }
    else                  { src = w2; dst = o2; off = i - 2883584; }
    float4 f = reinterpret_cast<const float4*>(src)[off];
    ushort4 o;
    o.x = f2bf(f.x); o.y = f2bf(f.y); o.z = f2bf(f.z); o.w = f2bf(f.w);
    reinterpret_cast<ushort4*>(dst)[off] = o;
}

// C = A[M,K] * Bw[N,K]^T ; MODE 0: scatter to Q/K/V bf16 (q scaled by 0.125*log2e), MODE 1: fp32 out + bias
// This round: double-buffered LDS staging (STAGE next -> COMPUTE current -> sync),
// the exact pattern proven correct for 14 rounds in the attn kernel. Hides the
// per-K-step global_load_lds latency that the old single-buffer loop exposed 32x.
template<int MODE>
__global__ __launch_bounds__(256)
void gemm_bt(const unsigned short* __restrict__ A,
             const unsigned short* __restrict__ Bw,
             const float* __restrict__ bias,
             unsigned short* __restrict__ oQ,
             unsigned short* __restrict__ oK,
             unsigned short* __restrict__ oV,
             float* __restrict__ oF)
{
    __shared__ unsigned char sA[2][8192];
    __shared__ unsigned char sB[2][8192];
    const int tid = threadIdx.x;
    const int wid = tid >> 6, lane = tid & 63;
    const int g = lane >> 4, lr = lane & 15;
    const int wr = wid >> 1, wc = wid & 1;
    const int m0 = blockIdx.y * 128, n0 = blockIdx.x * 128;
    const int K = CEMB;

    f32x4 acc[4][4];
    #pragma unroll
    for (int i = 0; i < 4; i++)
        #pragma unroll
        for (int j = 0; j < 4; j++)
            #pragma unroll
            for (int r = 0; r < 4; r++) acc[i][j][r] = 0.f;

    const char* Ab = (const char*)A;
    const char* Bb = (const char*)Bw;

    // loop-invariant staging source offsets (same formulas as before)
    int o0 = tid * 16;
    int fs0 = o0 ^ (((o0 >> 7) & 3) << 4);
    int o1 = 4096 + tid * 16;
    int fs1 = o1 ^ (((o1 >> 7) & 3) << 4);
    const int row0 = fs0 >> 6, cb0 = fs0 & 63;
    const int row1 = fs1 >> 6, cb1 = fs1 & 63;
    const char* Abase0 = Ab + (size_t)(m0 + row0) * (K * 2) + cb0;
    const char* Abase1 = Ab + (size_t)(m0 + row1) * (K * 2) + cb1;
    const char* Bbase0 = Bb + (size_t)(n0 + row0) * (K * 2) + cb0;
    const char* Bbase1 = Bb + (size_t)(n0 + row1) * (K * 2) + cb1;

#define GSTAGE(BUF, K0)                                                      \
    {                                                                        \
        GLL16(Abase0 + (size_t)(K0) * 2, &sA[BUF][wid * 1024]);              \
        GLL16(Abase1 + (size_t)(K0) * 2, &sA[BUF][4096 + wid * 1024]);       \
        GLL16(Bbase0 + (size_t)(K0) * 2, &sB[BUF][wid * 1024]);              \
        GLL16(Bbase1 + (size_t)(K0) * 2, &sB[BUF][4096 + wid * 1024]);       \
    }

#define GCOMPUTE(BUF)                                                        \
    {                                                                        \
        bf16x8 af[4], bfr[4];                                                \
        _Pragma("unroll")                                                    \
        for (int mi = 0; mi < 4; mi++) {                                     \
            int row = wr * 64 + mi * 16 + lr;                                \
            int addr = row * 64 + ((g * 16) ^ (((row >> 1) & 3) << 4));      \
            af[mi] = *(const bf16x8*)(&sA[BUF][addr]);                       \
        }                                                                    \
        _Pragma("unroll")                                                    \
        for (int ni = 0; ni < 4; ni++) {                                     \
            int row = wc * 64 + ni * 16 + lr;                                \
            int addr = row * 64 + ((g * 16) ^ (((row >> 1) & 3) << 4));      \
            bfr[ni] = *(const bf16x8*)(&sB[BUF][addr]);                      \
        }                                                                    \
        _Pragma("unroll")                                                    \
        for (int mi = 0; mi < 4; mi++)                                       \
            _Pragma("unroll")                                                \
            for (int ni = 0; ni < 4; ni++)                                   \
                acc[mi][ni] = mfma16(af[mi], bfr[ni], acc[mi][ni]);          \
    }

    GSTAGE(0, 0);
    __syncthreads();
    for (int k0 = 0; k0 < K; k0 += 64) {
        GSTAGE(1, k0 + 32);                // k0+32 <= 992 < K always
        GCOMPUTE(0);
        __syncthreads();
        if (k0 + 64 < K) GSTAGE(0, k0 + 64);
        GCOMPUTE(1);
        __syncthreads();
    }
#undef GSTAGE
#undef GCOMPUTE

    #pragma unroll
    for (int mi = 0; mi < 4; mi++) {
        #pragma unroll
        for (int ni = 0; ni < 4; ni++) {
            int c = n0 + wc * 64 + ni * 16 + lr;
            float bv = bias[c];
            #pragma unroll
            for (int r = 0; r < 4; r++) {
                int m = m0 + wr * 64 + mi * 16 + g * 4 + r;
                float v = acc[mi][ni][r] + bv;
                if (MODE == 0) {
                    int sec = c >> 10, h = (c >> 6) & 15, d = c & 63;
                    int t = m >> 2, b = m & 3;
                    size_t addr = ((size_t)(b * NH + h) * SEQ_T + t) * DH + d;
                    // Q scaled by 1/sqrt(D) * log2(e) so attention works in exp2 domain
                    unsigned short val = f2bf(sec == 0 ? v * (0.125f * 1.44269504f) : v);
                    if (sec == 0) oQ[addr] = val;
                    else if (sec == 1) oK[addr] = val;
                    else oV[addr] = val;
                } else {
                    oF[(size_t)m * CEMB + c] = v;
                }
            }
        }
    }
}

// V [BH][T][64] -> VT [BH][64][T]
__global__ void vtrans(const unsigned short* __restrict__ V, unsigned short* __restrict__ VT) {
    __shared__ unsigned short tile[64][72];
    const int bh = blockIdx.y, t0 = blockIdx.x * 64;
    const int tid = threadIdx.x;
    const unsigned short* src = V + ((size_t)bh * SEQ_T + t0) * DH;
    #pragma unroll
    for (int r = 0; r < 2; r++) {
        int e = r * 2048 + tid * 8;
        u16x8 v = *(const u16x8*)(src + e);
        int row = e >> 6, col = e & 63;
        *(u16x8*)&tile[row][col] = v;
    }
    __syncthreads();
    unsigned short* dst = VT + (size_t)bh * DH * SEQ_T + t0;
    #pragma unroll
    for (int r = 0; r < 2; r++) {
        int e = r * 2048 + tid * 8;
        int d = e >> 6, tc = e & 63;
        u16x8 o;
        #pragma unroll
        for (int j = 0; j < 8; j++) o[j] = tile[tc + j][d];
        *(u16x8*)(dst + (size_t)d * SEQ_T + tc) = o;
    }
}

// Flash attention — BYTE-IDENTICAL to the proven r16/r18 kernel (210.5-211.2us,
// absmax 1.95e-3, verified 4x). See constraint ledger in r18.
__global__ __launch_bounds__(256, 4)
void attn(const unsigned short* __restrict__ Qg,
          const unsigned short* __restrict__ Kg,
          const unsigned short* __restrict__ VTg,
          unsigned short* __restrict__ CTX)
{
    __shared__ unsigned char sK[24576];   // bufs at 0/8192, 8KB pad (occupancy cap: 3 blocks/CU)
    __shared__ unsigned char sV[24576];

    const int id = blockIdx.x;
    const int swz = (id & 7) * 128 + (id >> 3);   // XCD swizzle: each bh's 16 blocks on one XCD
    const int bh = swz >> 4, qblk = swz & 15;
    const int q0 = qblk * 128;
    const int tid = threadIdx.x, wid = tid >> 6, lane = tid & 63;
    const int ql = lane & 31, h = lane >> 5;

    const char* Kb = (const char*)(Kg + (size_t)bh * SEQ_T * DH);
    const char* Vb = (const char*)(VTg + (size_t)bh * DH * SEQ_T);
    const unsigned short* Qb = Qg + (size_t)bh * SEQ_T * DH;

    // Q B-frags: Q[q0+wid*32+ql][s*16 + h*8 ..+8)
    const unsigned short* Qrow = Qb + (size_t)(q0 + wid * 32 + ql) * DH;
    const bf16x8 qf0 = *(const bf16x8*)(Qrow + 0 + h * 8);
    const bf16x8 qf1 = *(const bf16x8*)(Qrow + 16 + h * 8);
    const bf16x8 qf2 = *(const bf16x8*)(Qrow + 32 + h * 8);
    const bf16x8 qf3 = *(const bf16x8*)(Qrow + 48 + h * 8);

    // ones B-frag for row-sum MFMA (bf16 1.0 = 0x3F80)
    bf16x8 onesv;
    #pragma unroll
    for (int j = 0; j < 8; j++) onesv[j] = (short)0x3F80;

    // loop-invariant zero C-operand (kZERO hoist, proven r13)
    f32x16 kZERO;
    #pragma unroll
    for (int r = 0; r < 16; r++) kZERO[r] = 0.f;

    f32x16 ctx0, ctx1, ctxS;
    #pragma unroll
    for (int r = 0; r < 16; r++) { ctx0[r] = 0.f; ctx1[r] = 0.f; ctxS[r] = 0.f; }

    // ---- loop-invariant LDS read offsets ----
    const int swk = (ql & 7) << 4;
    const int kOff0 = ql * 128 + ((0 * 32 + h * 16) ^ swk);
    const int kOff1 = ql * 128 + ((1 * 32 + h * 16) ^ swk);
    const int kOff2 = ql * 128 + ((2 * 32 + h * 16) ^ swk);
    const int kOff3 = ql * 128 + ((3 * 32 + h * 16) ^ swk);
    // PV V-read offsets: slot map k=16t+8h+j -> V[d=ql][bytes 32t+16h ..+16)
    int vX[4];
    #pragma unroll
    for (int t = 0; t < 4; t++)
        vX[t] = ql * 128 + ((t * 32 + 16 * h) ^ swk);

    // ---- loop-invariant staging source bases (s0-additive) ----
    int o0 = tid * 16;
    int f0 = o0 ^ (((o0 >> 7) & 7) << 4);
    int o1 = 4096 + tid * 16;
    int f1 = o1 ^ (((o1 >> 7) & 7) << 4);
    const char* kbase0 = Kb + (size_t)(f0 >> 7) * 128 + (f0 & 127);
    const char* kbase1 = Kb + (size_t)(f1 >> 7) * 128 + (f1 & 127);
    const char* vbase0 = Vb + (size_t)(f0 >> 7) * (SEQ_T * 2) + (f0 & 127);
    const char* vbase1 = Vb + (size_t)(f1 >> 7) * (SEQ_T * 2) + (f1 & 127);

#define STAGE(BUF, S0)                                                       \
    {                                                                        \
        GLL16(kbase0 + (size_t)(S0) * 128, sK + (BUF) * 8192 + wid * 1024);  \
        GLL16(kbase1 + (size_t)(S0) * 128, sK + (BUF) * 8192 + 4096 + wid * 1024); \
        GLL16(vbase0 + (size_t)(S0) * 2, sV + (BUF) * 8192 + wid * 1024);    \
        GLL16(vbase1 + (size_t)(S0) * 2, sV + (BUF) * 8192 + 4096 + wid * 1024); \
    }

#define LD8(p) (*(const bf16x8*)(p))

#define ATTN_TILE(BUF)                                                       \
    {                                                                        \
        const unsigned char* kb = sK + (BUF) * 8192;                         \
        const unsigned char* vb = sV + (BUF) * 8192;                         \
        __builtin_amdgcn_s_setprio(1);                                       \
        f32x16 S0 = mfma32(LD8(kb + kOff0), qf0, kZERO);                     \
        S0 = mfma32(LD8(kb + kOff1), qf1, S0);                               \
        S0 = mfma32(LD8(kb + kOff2), qf2, S0);                               \
        S0 = mfma32(LD8(kb + kOff3), qf3, S0);                               \
        f32x16 S1 = mfma32(LD8(kb + 4096 + kOff0), qf0, kZERO);              \
        S1 = mfma32(LD8(kb + 4096 + kOff1), qf1, S1);                        \
        S1 = mfma32(LD8(kb + 4096 + kOff2), qf2, S1);                        \
        S1 = mfma32(LD8(kb + 4096 + kOff3), qf3, S1);                        \
        __builtin_amdgcn_s_setprio(0);                                       \
        _Pragma("unroll")                                                    \
        for (int r = 0; r < 16; r++) S0[r] = exp2fast(S0[r]);                \
        _Pragma("unroll")                                                    \
        for (int r = 0; r < 16; r++) S1[r] = exp2fast(S1[r]);                \
        unsigned pw[16];                                                     \
        _Pragma("unroll")                                                    \
        for (int w = 0; w < 8; w++) pw[w] = cvtpk(S0[2 * w], S0[2 * w + 1]); \
        _Pragma("unroll")                                                    \
        for (int w = 0; w < 8; w++) pw[8 + w] = cvtpk(S1[2 * w], S1[2 * w + 1]); \
        __builtin_amdgcn_s_setprio(1);                                       \
        _Pragma("unroll")                                                    \
        for (int t = 0; t < 4; t++) {                                        \
            unsigned a0 = pw[4 * t],     a1 = pw[4 * t + 2];                 \
            unsigned b0 = pw[4 * t + 1], b1 = pw[4 * t + 3];                 \
            asm("v_permlane32_swap_b32 %0, %1" : "+v"(a0), "+v"(a1));        \
            asm("v_permlane32_swap_b32 %0, %1" : "+v"(b0), "+v"(b1));        \
            union { unsigned u[4]; bf16x8 v; } pa;                           \
            pa.u[0] = a0; pa.u[1] = b0; pa.u[2] = a1; pa.u[3] = b1;          \
            ctx0 = mfma32(pa.v, LD8(vb + vX[t]), ctx0);                      \
            ctx1 = mfma32(pa.v, LD8(vb + 4096 + vX[t]), ctx1);               \
            ctxS = mfma32(pa.v, onesv, ctxS);  /* row-sum in matrix pipe */  \
        }                                                                    \
        __builtin_amdgcn_s_setprio(0);                                       \
    }

    STAGE(0, 0);
    __syncthreads();
    for (int s0 = 0; s0 < SEQ_T; s0 += 128) {
        STAGE(1, s0 + 64);
        ATTN_TILE(0);
        __syncthreads();
        if (s0 + 128 < SEQ_T) STAGE(0, s0 + 128);
        ATTN_TILE(1);
        __syncthreads();
    }

    // ctx layout: lane holds ctx[q=(r&3)+8*(r>>2)+4h][d = ql (+32 for ctx1)];
    // ctxS[r] = row-sum for that q (all cols identical).
    const int b = bh >> 4, hh = bh & 15;
    #pragma unroll
    for (int r = 0; r < 16; r++) {
        int qq = (r & 3) + 8 * (r >> 2) + 4 * h;
        float inv = __builtin_amdgcn_rcpf(ctxS[r]);
        int tg = q0 + wid * 32 + qq;
        size_t rowbase = (size_t)(tg * 4 + b) * CEMB + hh * 64;
        CTX[rowbase + ql] = f2bf(ctx0[r] * inv);
        CTX[rowbase + 32 + ql] = f2bf(ctx1[r] * inv);
    }
#undef STAGE
#undef LD8
#undef ATTN_TILE
}

extern "C" void kernel_launch(void* const* d_in, const int* in_sizes, int n_in,
                              void* d_out, int out_size, void* d_ws, size_t ws_size,
                              hipStream_t stream) {
    const float* query  = (const float*)d_in[0];
    const float* w_in   = (const float*)d_in[1];
    const float* b_in   = (const float*)d_in[2];
    const float* w_out  = (const float*)d_in[3];
    const float* b_out  = (const float*)d_in[4];
    float* out = (float*)d_out;

    char* ws = (char*)d_ws;
    unsigned short* Xbf  = (unsigned short*)(ws);
    unsigned short* Wqkv = (unsigned short*)(ws + 16777216);
    unsigned short* Wout = (unsigned short*)(ws + 23068672);
    unsigned short* Q    = (unsigned short*)(ws + 25165824);
    unsigned short* K    = (unsigned short*)(ws + 41943040);
    unsigned short* V    = (unsigned short*)(ws + 58720256);
    unsigned short* VT   = (unsigned short*)(ws + 75497472);
    unsigned short* CTX  = (unsigned short*)(ws + 92274688);

    cast_all<<<12288, 256, 0, stream>>>(query, w_in, w_out, Xbf, Wqkv, Wout);

    gemm_bt<0><<<dim3(24, 64), 256, 0, stream>>>(Xbf, Wqkv, b_in, Q, K, V, nullptr);
    vtrans<<<dim3(32, 64), 256, 0, stream>>>(V, VT);
    attn<<<1024, 256, 0, stream>>>(Q, K, VT, CTX);
    gemm_bt<1><<<dim3(8, 64), 256, 0, stream>>>(CTX, Wout, b_out, nullptr, nullptr, nullptr, out);
}

// Round 20
// 210.398 us; speedup vs baseline: 1.0294x; 1.0294x over previous
//
#include <hip/hip_runtime.h>
#include <hip/hip_bf16.h>
#include <stdint.h>

#define SEQ_T 2048
#define NBATCH 4
#define CEMB 1024
#define NH 16
#define DH 64
#define MROWS 8192

typedef short bf16x8 __attribute__((ext_vector_type(8)));
typedef float f32x4 __attribute__((ext_vector_type(4)));
typedef float f32x16 __attribute__((ext_vector_type(16)));
typedef unsigned short u16x8 __attribute__((ext_vector_type(8)));
typedef unsigned int u32x2 __attribute__((ext_vector_type(2)));

__device__ __forceinline__ unsigned short f2bf(float f) {
    union { float f; unsigned u; } v; v.f = f;
    unsigned r = (v.u + 0x7FFFu + ((v.u >> 16) & 1u)) >> 16;
    return (unsigned short)r;
}

__device__ __forceinline__ f32x4 mfma16(bf16x8 a, bf16x8 b, f32x4 c) {
    return __builtin_amdgcn_mfma_f32_16x16x32_bf16(a, b, c, 0, 0, 0);
}
__device__ __forceinline__ f32x16 mfma32(bf16x8 a, bf16x8 b, f32x16 c) {
    return __builtin_amdgcn_mfma_f32_32x32x16_bf16(a, b, c, 0, 0, 0);
}

__device__ __forceinline__ float exp2fast(float x) {
    float r; asm("v_exp_f32 %0, %1" : "=v"(r) : "v"(x)); return r;
}
// packed bf16 RNE convert: dst = {bf16(lo), bf16(hi)}
__device__ __forceinline__ unsigned cvtpk(float lo, float hi) {
    unsigned r;
    asm("v_cvt_pk_bf16_f32 %0, %1, %2" : "=v"(r) : "v"(lo), "v"(hi));
    return r;
}

#define GLL16(g, l) __builtin_amdgcn_global_load_lds( \
    (const __attribute__((address_space(1))) void*)(g), \
    (__attribute__((address_space(3))) void*)(l), 16, 0, 0)

// Single fused cast: X (2097152 f4) | Wqkv (786432 f4) | Wout (262144 f4)
__global__ __launch_bounds__(256)
void cast_all(const float* __restrict__ x, const float* __restrict__ w1,
              const float* __restrict__ w2,
              unsigned short* __restrict__ ox, unsigned short* __restrict__ o1,
              unsigned short* __restrict__ o2) {
    int i = blockIdx.x * blockDim.x + threadIdx.x;
    const float* src; unsigned short* dst; int off;
    if (i < 2097152)      { src = x;  dst = ox; off = i; }
    else if (i < 2883584) { src = w1; dst = o1; off = i - 2097152; }
    else                  { src = w2; dst = o2; off = i - 2883584; }
    float4 f = reinterpret_cast<const float4*>(src)[off];
    ushort4 o;
    o.x = f2bf(f.x); o.y = f2bf(f.y); o.z = f2bf(f.z); o.w = f2bf(f.w);
    reinterpret_cast<ushort4*>(dst)[off] = o;
}

// C = A[M,K] * Bw[N,K]^T ; MODE 0: scatter to Q/K/V bf16 (q scaled by 0.125*log2e), MODE 1: fp32 out + bias
// Single-buffered staging loop is the PROVEN optimum: r19's explicit double-buffer
// (32KB LDS) regressed 211.0 -> 216.6us — implicit wave-level overlap at 16KB LDS /
// high occupancy already hides staging latency (matches learn_hip m99/m100).
template<int MODE>
__global__ __launch_bounds__(256)
void gemm_bt(const unsigned short* __restrict__ A,
             const unsigned short* __restrict__ Bw,
             const float* __restrict__ bias,
             unsigned short* __restrict__ oQ,
             unsigned short* __restrict__ oK,
             unsigned short* __restrict__ oV,
             float* __restrict__ oF)
{
    __shared__ unsigned char sA[8192];
    __shared__ unsigned char sB[8192];
    const int tid = threadIdx.x;
    const int wid = tid >> 6, lane = tid & 63;
    const int g = lane >> 4, lr = lane & 15;
    const int wr = wid >> 1, wc = wid & 1;
    const int m0 = blockIdx.y * 128, n0 = blockIdx.x * 128;
    const int K = CEMB;

    f32x4 acc[4][4];
    #pragma unroll
    for (int i = 0; i < 4; i++)
        #pragma unroll
        for (int j = 0; j < 4; j++)
            #pragma unroll
            for (int r = 0; r < 4; r++) acc[i][j][r] = 0.f;

    const char* Ab = (const char*)A;
    const char* Bb = (const char*)Bw;

    for (int k0 = 0; k0 < K; k0 += 32) {
        #pragma unroll
        for (int r2 = 0; r2 < 2; r2++) {
            int o = r2 * 4096 + tid * 16;
            int f = o ^ (((o >> 7) & 3) << 4);     // inverse swizzle on source
            int row = f >> 6, cb = f & 63;
            GLL16(Ab + (size_t)(m0 + row) * (K * 2) + k0 * 2 + cb, sA + r2 * 4096 + wid * 1024);
            GLL16(Bb + (size_t)(n0 + row) * (K * 2) + k0 * 2 + cb, sB + r2 * 4096 + wid * 1024);
        }
        __syncthreads();
        bf16x8 af[4], bfr[4];
        #pragma unroll
        for (int mi = 0; mi < 4; mi++) {
            int row = wr * 64 + mi * 16 + lr;
            int addr = row * 64 + ((g * 16) ^ (((row >> 1) & 3) << 4));
            af[mi] = *(const bf16x8*)(sA + addr);
        }
        #pragma unroll
        for (int ni = 0; ni < 4; ni++) {
            int row = wc * 64 + ni * 16 + lr;
            int addr = row * 64 + ((g * 16) ^ (((row >> 1) & 3) << 4));
            bfr[ni] = *(const bf16x8*)(sB + addr);
        }
        #pragma unroll
        for (int mi = 0; mi < 4; mi++)
            #pragma unroll
            for (int ni = 0; ni < 4; ni++)
                acc[mi][ni] = mfma16(af[mi], bfr[ni], acc[mi][ni]);
        __syncthreads();
    }

    #pragma unroll
    for (int mi = 0; mi < 4; mi++) {
        #pragma unroll
        for (int ni = 0; ni < 4; ni++) {
            int c = n0 + wc * 64 + ni * 16 + lr;
            float bv = bias[c];
            #pragma unroll
            for (int r = 0; r < 4; r++) {
                int m = m0 + wr * 64 + mi * 16 + g * 4 + r;
                float v = acc[mi][ni][r] + bv;
                if (MODE == 0) {
                    int sec = c >> 10, h = (c >> 6) & 15, d = c & 63;
                    int t = m >> 2, b = m & 3;
                    size_t addr = ((size_t)(b * NH + h) * SEQ_T + t) * DH + d;
                    // Q scaled by 1/sqrt(D) * log2(e) so attention works in exp2 domain
                    unsigned short val = f2bf(sec == 0 ? v * (0.125f * 1.44269504f) : v);
                    if (sec == 0) oQ[addr] = val;
                    else if (sec == 1) oK[addr] = val;
                    else oV[addr] = val;
                } else {
                    oF[(size_t)m * CEMB + c] = v;
                }
            }
        }
    }
}

// V [BH][T][64] -> VT [BH][64][T]
__global__ void vtrans(const unsigned short* __restrict__ V, unsigned short* __restrict__ VT) {
    __shared__ unsigned short tile[64][72];
    const int bh = blockIdx.y, t0 = blockIdx.x * 64;
    const int tid = threadIdx.x;
    const unsigned short* src = V + ((size_t)bh * SEQ_T + t0) * DH;
    #pragma unroll
    for (int r = 0; r < 2; r++) {
        int e = r * 2048 + tid * 8;
        u16x8 v = *(const u16x8*)(src + e);
        int row = e >> 6, col = e & 63;
        *(u16x8*)&tile[row][col] = v;
    }
    __syncthreads();
    unsigned short* dst = VT + (size_t)bh * DH * SEQ_T + t0;
    #pragma unroll
    for (int r = 0; r < 2; r++) {
        int e = r * 2048 + tid * 8;
        int d = e >> 6, tc = e & 63;
        u16x8 o;
        #pragma unroll
        for (int j = 0; j < 8; j++) o[j] = tile[tc + j][d];
        *(u16x8*)(dst + (size_t)d * SEQ_T + tc) = o;
    }
}

// Flash attention, 32x32 swapped form, softmax fully in-register, no max tracking.
// FINAL proven configuration (r13/r16/r18: total 210.4-211.2us, absmax 1.95e-3,
// verified 4x). Constraint ledger (rounds 5-7, 11, 14, 15, 17 failed correctness;
// r19 gemm-dbuf regressed perf):
//   - toxic: column-granule wide-stride staging sources; 40KB LDS (even with
//     explicit vmcnt(0)+lgkmcnt(0) hardened barriers — r17); 512-thr/8-wave
//     blocks; 2-deep q per wave at 2 blocks/CU. Mechanism not observable from
//     HIP source (requires disassembly).
//   - safe & applied: swapped-QK^T in-register softmax (no LDS P round-trip),
//     exp2-domain Q pre-scale, ones-MFMA row-sum (matrix pipe), b128 V reads
//     via permlane32_swap positional k-map, kZERO C-operand hoist, raw
//     v_exp_f32 / v_cvt_pk_bf16_f32, loop-invariant LDS offsets, XCD swizzle,
//     48KB LDS (3 blocks/CU for L2 residency; FETCH 24.6MB).
__global__ __launch_bounds__(256, 4)
void attn(const unsigned short* __restrict__ Qg,
          const unsigned short* __restrict__ Kg,
          const unsigned short* __restrict__ VTg,
          unsigned short* __restrict__ CTX)
{
    __shared__ unsigned char sK[24576];   // bufs at 0/8192, 8KB pad (occupancy cap: 3 blocks/CU)
    __shared__ unsigned char sV[24576];

    const int id = blockIdx.x;
    const int swz = (id & 7) * 128 + (id >> 3);   // XCD swizzle: each bh's 16 blocks on one XCD
    const int bh = swz >> 4, qblk = swz & 15;
    const int q0 = qblk * 128;
    const int tid = threadIdx.x, wid = tid >> 6, lane = tid & 63;
    const int ql = lane & 31, h = lane >> 5;

    const char* Kb = (const char*)(Kg + (size_t)bh * SEQ_T * DH);
    const char* Vb = (const char*)(VTg + (size_t)bh * DH * SEQ_T);
    const unsigned short* Qb = Qg + (size_t)bh * SEQ_T * DH;

    // Q B-frags: Q[q0+wid*32+ql][s*16 + h*8 ..+8)
    const unsigned short* Qrow = Qb + (size_t)(q0 + wid * 32 + ql) * DH;
    const bf16x8 qf0 = *(const bf16x8*)(Qrow + 0 + h * 8);
    const bf16x8 qf1 = *(const bf16x8*)(Qrow + 16 + h * 8);
    const bf16x8 qf2 = *(const bf16x8*)(Qrow + 32 + h * 8);
    const bf16x8 qf3 = *(const bf16x8*)(Qrow + 48 + h * 8);

    // ones B-frag for row-sum MFMA (bf16 1.0 = 0x3F80)
    bf16x8 onesv;
    #pragma unroll
    for (int j = 0; j < 8; j++) onesv[j] = (short)0x3F80;

    // loop-invariant zero C-operand (kZERO hoist, proven r13)
    f32x16 kZERO;
    #pragma unroll
    for (int r = 0; r < 16; r++) kZERO[r] = 0.f;

    f32x16 ctx0, ctx1, ctxS;
    #pragma unroll
    for (int r = 0; r < 16; r++) { ctx0[r] = 0.f; ctx1[r] = 0.f; ctxS[r] = 0.f; }

    // ---- loop-invariant LDS read offsets ----
    const int swk = (ql & 7) << 4;
    const int kOff0 = ql * 128 + ((0 * 32 + h * 16) ^ swk);
    const int kOff1 = ql * 128 + ((1 * 32 + h * 16) ^ swk);
    const int kOff2 = ql * 128 + ((2 * 32 + h * 16) ^ swk);
    const int kOff3 = ql * 128 + ((3 * 32 + h * 16) ^ swk);
    // PV V-read offsets: slot map k=16t+8h+j -> V[d=ql][bytes 32t+16h ..+16)
    int vX[4];
    #pragma unroll
    for (int t = 0; t < 4; t++)
        vX[t] = ql * 128 + ((t * 32 + 16 * h) ^ swk);

    // ---- loop-invariant staging source bases (s0-additive) ----
    int o0 = tid * 16;
    int f0 = o0 ^ (((o0 >> 7) & 7) << 4);
    int o1 = 4096 + tid * 16;
    int f1 = o1 ^ (((o1 >> 7) & 7) << 4);
    const char* kbase0 = Kb + (size_t)(f0 >> 7) * 128 + (f0 & 127);
    const char* kbase1 = Kb + (size_t)(f1 >> 7) * 128 + (f1 & 127);
    const char* vbase0 = Vb + (size_t)(f0 >> 7) * (SEQ_T * 2) + (f0 & 127);
    const char* vbase1 = Vb + (size_t)(f1 >> 7) * (SEQ_T * 2) + (f1 & 127);

#define STAGE(BUF, S0)                                                       \
    {                                                                        \
        GLL16(kbase0 + (size_t)(S0) * 128, sK + (BUF) * 8192 + wid * 1024);  \
        GLL16(kbase1 + (size_t)(S0) * 128, sK + (BUF) * 8192 + 4096 + wid * 1024); \
        GLL16(vbase0 + (size_t)(S0) * 2, sV + (BUF) * 8192 + wid * 1024);    \
        GLL16(vbase1 + (size_t)(S0) * 2, sV + (BUF) * 8192 + 4096 + wid * 1024); \
    }

#define LD8(p) (*(const bf16x8*)(p))

#define ATTN_TILE(BUF)                                                       \
    {                                                                        \
        const unsigned char* kb = sK + (BUF) * 8192;                         \
        const unsigned char* vb = sV + (BUF) * 8192;                         \
        __builtin_amdgcn_s_setprio(1);                                       \
        f32x16 S0 = mfma32(LD8(kb + kOff0), qf0, kZERO);                     \
        S0 = mfma32(LD8(kb + kOff1), qf1, S0);                               \
        S0 = mfma32(LD8(kb + kOff2), qf2, S0);                               \
        S0 = mfma32(LD8(kb + kOff3), qf3, S0);                               \
        f32x16 S1 = mfma32(LD8(kb + 4096 + kOff0), qf0, kZERO);              \
        S1 = mfma32(LD8(kb + 4096 + kOff1), qf1, S1);                        \
        S1 = mfma32(LD8(kb + 4096 + kOff2), qf2, S1);                        \
        S1 = mfma32(LD8(kb + 4096 + kOff3), qf3, S1);                        \
        __builtin_amdgcn_s_setprio(0);                                       \
        _Pragma("unroll")                                                    \
        for (int r = 0; r < 16; r++) S0[r] = exp2fast(S0[r]);                \
        _Pragma("unroll")                                                    \
        for (int r = 0; r < 16; r++) S1[r] = exp2fast(S1[r]);                \
        unsigned pw[16];                                                     \
        _Pragma("unroll")                                                    \
        for (int w = 0; w < 8; w++) pw[w] = cvtpk(S0[2 * w], S0[2 * w + 1]); \
        _Pragma("unroll")                                                    \
        for (int w = 0; w < 8; w++) pw[8 + w] = cvtpk(S1[2 * w], S1[2 * w + 1]); \
        __builtin_amdgcn_s_setprio(1);                                       \
        _Pragma("unroll")                                                    \
        for (int t = 0; t < 4; t++) {                                        \
            unsigned a0 = pw[4 * t],     a1 = pw[4 * t + 2];                 \
            unsigned b0 = pw[4 * t + 1], b1 = pw[4 * t + 3];                 \
            asm("v_permlane32_swap_b32 %0, %1" : "+v"(a0), "+v"(a1));        \
            asm("v_permlane32_swap_b32 %0, %1" : "+v"(b0), "+v"(b1));        \
            union { unsigned u[4]; bf16x8 v; } pa;                           \
            pa.u[0] = a0; pa.u[1] = b0; pa.u[2] = a1; pa.u[3] = b1;          \
            ctx0 = mfma32(pa.v, LD8(vb + vX[t]), ctx0);                      \
            ctx1 = mfma32(pa.v, LD8(vb + 4096 + vX[t]), ctx1);               \
            ctxS = mfma32(pa.v, onesv, ctxS);  /* row-sum in matrix pipe */  \
        }                                                                    \
        __builtin_amdgcn_s_setprio(0);                                       \
    }

    STAGE(0, 0);
    __syncthreads();
    for (int s0 = 0; s0 < SEQ_T; s0 += 128) {
        STAGE(1, s0 + 64);
        ATTN_TILE(0);
        __syncthreads();
        if (s0 + 128 < SEQ_T) STAGE(0, s0 + 128);
        ATTN_TILE(1);
        __syncthreads();
    }

    // ctx layout: lane holds ctx[q=(r&3)+8*(r>>2)+4h][d = ql (+32 for ctx1)];
    // ctxS[r] = row-sum for that q (all cols identical).
    const int b = bh >> 4, hh = bh & 15;
    #pragma unroll
    for (int r = 0; r < 16; r++) {
        int qq = (r & 3) + 8 * (r >> 2) + 4 * h;
        float inv = __builtin_amdgcn_rcpf(ctxS[r]);
        int tg = q0 + wid * 32 + qq;
        size_t rowbase = (size_t)(tg * 4 + b) * CEMB + hh * 64;
        CTX[rowbase + ql] = f2bf(ctx0[r] * inv);
        CTX[rowbase + 32 + ql] = f2bf(ctx1[r] * inv);
    }
#undef STAGE
#undef LD8
#undef ATTN_TILE
}

extern "C" void kernel_launch(void* const* d_in, const int* in_sizes, int n_in,
                              void* d_out, int out_size, void* d_ws, size_t ws_size,
                              hipStream_t stream) {
    const float* query  = (const float*)d_in[0];
    const float* w_in   = (const float*)d_in[1];
    const float* b_in   = (const float*)d_in[2];
    const float* w_out  = (const float*)d_in[3];
    const float* b_out  = (const float*)d_in[4];
    float* out = (float*)d_out;

    char* ws = (char*)d_ws;
    unsigned short* Xbf  = (unsigned short*)(ws);
    unsigned short* Wqkv = (unsigned short*)(ws + 16777216);
    unsigned short* Wout = (unsigned short*)(ws + 23068672);
    unsigned short* Q    = (unsigned short*)(ws + 25165824);
    unsigned short* K    = (unsigned short*)(ws + 41943040);
    unsigned short* V    = (unsigned short*)(ws + 58720256);
    unsigned short* VT   = (unsigned short*)(ws + 75497472);
    unsigned short* CTX  = (unsigned short*)(ws + 92274688);

    cast_all<<<12288, 256, 0, stream>>>(query, w_in, w_out, Xbf, Wqkv, Wout);

    gemm_bt<0><<<dim3(24, 64), 256, 0, stream>>>(Xbf, Wqkv, b_in, Q, K, V, nullptr);
    vtrans<<<dim3(32, 64), 256, 0, stream>>>(V, VT);
    attn<<<1024, 256, 0, stream>>>(Q, K, VT, CTX);
    gemm_bt<1><<<dim3(8, 64), 256, 0, stream>>>(CTX, Wout, b_out, nullptr, nullptr, nullptr, out);
}